// Round 6
// baseline (165.362 us; speedup 1.0000x reference)
//
#include <hip/hip_runtime.h>

#define DIM     128
#define NCODES  1024
#define TILE_M  64
#define LDSS    136          // 128 + 8 halves pad: row stride 272 B = 17 x 16 B (2-way, free)
#define FLAGThr 0.018f       // acc-units: fp16 Hoeffding 0.010 + 2x pack err 0.008
#define RPB     4            // refine rows per block
#define RGRID   1024         // refine grid

typedef __attribute__((ext_vector_type(8))) _Float16 half8;
typedef __attribute__((ext_vector_type(4))) _Float16 half4;
typedef __attribute__((ext_vector_type(4))) float    f32x4;

// ws layout:
//      0 : e2d    (1024 double)          8 KB
//   8192 : e2f    (1024 float)           4 KB
//  12288 : eh     (1024*128 _Float16)  256 KB
// 274432 : embedT (128*1024 float)     512 KB
// 798720 : cnt    (int)
// 798976 : list   (65536 int)          256 KB

// -------- setup (fused prep+transpose): e2 f32/f64, eh fp16, embedT --------
__global__ __launch_bounds__(256) void setup_kernel(
    const float* __restrict__ embed, double* __restrict__ e2d,
    float* __restrict__ e2f, _Float16* __restrict__ eh,
    float* __restrict__ embedT, int* __restrict__ cnt)
{
  __shared__ float tile[64][132];            // 132: 16B-aligned rows, bank stride 4
  __shared__ double psum[4][64];
  if (blockIdx.x == 0 && threadIdx.x == 0) *cnt = 0;
  const int c0 = blockIdx.x * 64;            // 16 blocks x 64 codes
  const int t  = threadIdx.x;

  const f32x4* E4 = (const f32x4*)(embed + (size_t)c0 * DIM);
  #pragma unroll
  for (int i = 0; i < 8; ++i) {
    int e = t + i * 256;                     // 2048 float4s = 64x128
    int r = e >> 5, c4 = e & 31;
    f32x4 v = E4[e];
    *(f32x4*)&tile[r][c4 * 4] = v;
    half4 h;
    h[0] = (_Float16)v[0]; h[1] = (_Float16)v[1];
    h[2] = (_Float16)v[2]; h[3] = (_Float16)v[3];
    *(half4*)&eh[(size_t)(c0 + r) * DIM + c4 * 4] = h;
  }
  __syncthreads();

  // e2: 4 threads per code, 32 dims each
  {
    int r = t & 63, part = t >> 6;
    double s = 0.0;
    #pragma unroll
    for (int k = 0; k < 32; ++k) {
      float v = tile[r][part * 32 + k];
      s += (double)v * v;
    }
    psum[part][r] = s;
  }
  __syncthreads();
  if (t < 64) {
    double s = psum[0][t] + psum[1][t] + psum[2][t] + psum[3][t];
    e2d[c0 + t] = s;
    e2f[c0 + t] = (float)s;
  }

  // embedT[k][c0+c] = tile[c][k]; coalesced 256B segments per k-row
  #pragma unroll
  for (int i = 0; i < 32; ++i) {
    int idx = t + i * 256;                   // 8192 = 128k x 64c
    int k = idx >> 6, c = idx & 63;
    embedT[(size_t)k * NCODES + c0 + c] = tile[c][k];
  }
}

// -------- pass1 v5: 8 waves x (32 rows x 256 codes), e2 folded into acc ----
// acc = x.e - 0.5*e2 - 16  (init baked into MFMA C); argmax(acc) == argmin dist.
// Index packed into low 10 mantissa bits; for the (negative) acc range the
// packed tie-break prefers LOWER index, matching np.argmax-of-dist. Any row
// whose top-2 acc gap <= FLAGThr (covers fp16 rounding + packing + any
// sign-crossing tie anomaly) is re-decided exactly by refine2.
// Register budget (per wave): afrag 32 + bbuf 32 + best/sec 16 + misc ~18
//   -> <=128 total => 4 waves/SIMD, 2 blocks/CU, grid = 2 uniform rounds.
__global__ __launch_bounds__(512)
__attribute__((amdgpu_waves_per_eu(4)))
void pass1_kernel(
    const float* __restrict__ x, const float* __restrict__ embed,
    const _Float16* __restrict__ eh, const float* __restrict__ e2f,
    float* __restrict__ outQ, float* __restrict__ outIdx,
    int* __restrict__ cnt, int* __restrict__ list)
{
  __shared__ _Float16 xh[TILE_M * LDSS];
  __shared__ float rb_best[4][TILE_M];
  __shared__ float rb_sec [4][TILE_M];
  __shared__ int   fidx[TILE_M];

  const int tid  = threadIdx.x;
  const int row0 = blockIdx.x * TILE_M;

  // stage x tile (64x128 f32 -> fp16 LDS, padded stride)
  {
    const f32x4* x4 = (const f32x4*)(x + (size_t)row0 * DIM);
    #pragma unroll
    for (int i = 0; i < 4; ++i) {
      int e = tid + i * 512;                 // 2048 float4s
      int r = e >> 5, c4 = e & 31;
      f32x4 v = x4[e];
      half4 h;
      h[0] = (_Float16)v[0]; h[1] = (_Float16)v[1];
      h[2] = (_Float16)v[2]; h[3] = (_Float16)v[3];
      *(half4*)&xh[r * LDSS + c4 * 4] = h;
    }
  }
  __syncthreads();

  const int l  = tid & 63, w = tid >> 6;     // 8 waves
  const int rl = l & 15,  q = l >> 4;
  const int col0 = q * 8;
  const int rh = w >> 2;                     // row half   (0..1)
  const int cq = w & 3;                      // code quarter (0..3)

  // A fragments: 2 m-subs x 4 k-steps (32 rows), reused for 256 codes
  half8 afrag[2][4];
  #pragma unroll
  for (int m = 0; m < 2; ++m)
    #pragma unroll
    for (int ks = 0; ks < 4; ++ks)
      afrag[m][ks] = *(const half8*)&xh[(rh * 32 + m * 16 + rl) * LDSS + ks * 32 + col0];

  float bestp[8], secp[8];
  #pragma unroll
  for (int s = 0; s < 8; ++s) { bestp[s] = -3.0e38f; secp[s] = -3.3e38f; }

  const int codeBase = cq * 256;             // wave-private code range
  const _Float16* ehw = eh + (size_t)(codeBase + rl) * DIM + col0;

  // B register ping-pong (global fp16, L2-resident)
  half8 bbuf[2][4];
  float e2buf[2];
  #pragma unroll
  for (int ks = 0; ks < 4; ++ks) bbuf[0][ks] = *(const half8*)(ehw + ks * 32);
  e2buf[0] = e2f[codeBase + rl];

  #pragma unroll 2
  for (int ch = 0; ch < 16; ++ch) {
    const int cur = ch & 1, nxt = cur ^ 1;
    const int mycode = codeBase + ch * 16 + rl;
    if (ch < 15) {
      const _Float16* ehn = ehw + (size_t)(ch + 1) * (16 * DIM);
      #pragma unroll
      for (int ks = 0; ks < 4; ++ks) bbuf[nxt][ks] = *(const half8*)(ehn + ks * 32);
      e2buf[nxt] = e2f[mycode + 16];
    }
    // fold -0.5*e2 - 16 into the accumulator init (kills per-score fmaf)
    const float vinit = fmaf(-0.5f, e2buf[cur], -16.0f);

    #pragma unroll
    for (int m = 0; m < 2; ++m) {
      f32x4 acc = (f32x4){vinit, vinit, vinit, vinit};
      #pragma unroll
      for (int ks = 0; ks < 4; ++ks)
        acc = __builtin_amdgcn_mfma_f32_16x16x32_f16(afrag[m][ks], bbuf[cur][ks], acc, 0, 0, 0);
      #pragma unroll
      for (int r = 0; r < 4; ++r) {
        const int s = m * 4 + r;
        // pack index into low 10 mantissa bits: one v_and_or_b32
        float scp = __int_as_float((__float_as_int(acc[r]) & ~1023) | mycode);
        // top-2 MAX update: sec' = median(best, scp, sec); best' = max
        secp[s]  = __builtin_amdgcn_fmed3f(scp, bestp[s], secp[s]);
        bestp[s] = fmaxf(bestp[s], scp);
      }
    }
  }

  // merge across the 16 lanes of each quarter (same rows, different codes)
  #pragma unroll
  for (int off = 1; off < 16; off <<= 1) {
    #pragma unroll
    for (int s = 0; s < 8; ++s) {
      float ob = __shfl_xor(bestp[s], off, 16);
      float os = __shfl_xor(secp[s],  off, 16);
      // 2nd-largest of {b1,b2,s1,s2} = max(median(b1,b2,s1), s2)
      secp[s]  = fmaxf(__builtin_amdgcn_fmed3f(bestp[s], ob, secp[s]), os);
      bestp[s] = fmaxf(bestp[s], ob);
    }
  }
  if (rl == 0) {
    #pragma unroll
    for (int m = 0; m < 2; ++m)
      #pragma unroll
      for (int r = 0; r < 4; ++r) {
        int s = m * 4 + r;
        int row = rh * 32 + m * 16 + q * 4 + r;
        rb_best[cq][row] = bestp[s];
        rb_sec [cq][row] = secp[s];
      }
  }
  __syncthreads();

  // merge the 4 code-quarters, emit index + flag near-ties
  if (tid < TILE_M) {
    float bv = rb_best[0][tid], sv = rb_sec[0][tid];
    #pragma unroll
    for (int c2 = 1; c2 < 4; ++c2) {
      float ob = rb_best[c2][tid], os = rb_sec[c2][tid];
      sv = fmaxf(__builtin_amdgcn_fmed3f(bv, ob, sv), os);
      bv = fmaxf(bv, ob);
    }
    int bi = __float_as_int(bv) & 1023;
    int grow = row0 + tid;
    outIdx[grow] = (float)bi;
    fidx[tid] = bi;
    if (bv - sv <= FLAGThr) {
      int p = atomicAdd(cnt, 1);
      list[p] = grow;
    }
  }
  __syncthreads();

  // gather quantize = embed[idx] (coalesced writes, L2-hot embed reads)
  {
    const f32x4* E4   = (const f32x4*)embed;
    f32x4*       out4 = (f32x4*)(outQ + (size_t)row0 * DIM);
    #pragma unroll
    for (int i = 0; i < 4; ++i) {
      int e = tid + i * 512;
      int r = e >> 5, c4 = e & 31;
      out4[e] = E4[fidx[r] * 32 + c4];
    }
  }
}

// -------- refine v2: coalesced full f32 rescan via embedT, f64 decision -----
__global__ __launch_bounds__(256) void refine2_kernel(
    const float* __restrict__ x, const float* __restrict__ embed,
    const float* __restrict__ embedT,
    const double* __restrict__ e2d, const float* __restrict__ e2f,
    float* __restrict__ outQ, float* __restrict__ outIdx,
    const int* __restrict__ cnt, const int* __restrict__ list)
{
  __shared__ f32x4 xst[DIM];                 // xst[k][r]: k-th dim of row r
  __shared__ float rb1[RPB][4], rb2[RPB][4];
  __shared__ int   ri1[RPB][4], ri2[RPB][4];
  __shared__ int   cand[RPB][2];

  const int t = threadIdx.x;
  const int l = t & 63, w = t >> 6;
  const int n = *cnt;
  float* xsf = (float*)xst;

  for (int base = blockIdx.x * RPB; base < n; base += RGRID * RPB) {
    const int nr = min(RPB, n - base);
    // stage rows (transposed: xst[k][r])
    #pragma unroll
    for (int i = 0; i < 2; ++i) {
      int idx = t + i * 256;
      int r = idx >> 7, k = idx & 127;
      float v = 0.f;
      if (r < nr) v = x[(size_t)list[base + r] * DIM + k];
      xsf[k * RPB + r] = v;
    }
    __syncthreads();

    // thread t owns codes 4t..4t+3; fully coalesced embedT stream
    f32x4 dot[RPB];
    #pragma unroll
    for (int r = 0; r < RPB; ++r) dot[r] = (f32x4){0.f, 0.f, 0.f, 0.f};
    const f32x4* eT4 = (const f32x4*)embedT;
    #pragma unroll 4
    for (int k = 0; k < DIM; ++k) {
      f32x4 e4  = eT4[k * 256 + t];
      f32x4 xk4 = xst[k];
      #pragma unroll
      for (int r = 0; r < RPB; ++r) {
        dot[r][0] = fmaf(xk4[r], e4[0], dot[r][0]);
        dot[r][1] = fmaf(xk4[r], e4[1], dot[r][1]);
        dot[r][2] = fmaf(xk4[r], e4[2], dot[r][2]);
        dot[r][3] = fmaf(xk4[r], e4[3], dot[r][3]);
      }
    }

    // per-thread top-2 over its 4 codes, then wave + block merges
    #pragma unroll
    for (int r = 0; r < RPB; ++r) {
      float b1 = 3.4e38f, b2 = 3.4e38f; int i1 = 0, i2 = 0;
      #pragma unroll
      for (int j = 0; j < 4; ++j) {
        int c = 4 * t + j;
        float sc = fmaf(-2.0f, dot[r][j], e2f[c]);
        bool better = (sc < b1);                 // ties keep lower index
        float lv = better ? b1 : sc;  int li = better ? i1 : c;
        if (better) { b1 = sc; i1 = c; }
        bool t2 = (lv < b2) || (lv == b2 && li < i2);
        if (t2) { b2 = lv; i2 = li; }
      }
      #pragma unroll
      for (int off = 1; off < 64; off <<= 1) {
        float o1 = __shfl_xor(b1, off, 64); int oi1 = __shfl_xor(i1, off, 64);
        float o2 = __shfl_xor(b2, off, 64); int oi2 = __shfl_xor(i2, off, 64);
        bool take = (o1 < b1) || (o1 == b1 && oi1 < i1);
        float n1 = take ? o1 : b1; int ni1 = take ? oi1 : i1;
        float lo = take ? b1 : o1; int loi = take ? i1 : oi1;
        float c2v = take ? o2 : b2; int c2i = take ? oi2 : i2;
        bool u2 = (c2v < lo) || (c2v == lo && c2i < loi);
        b1 = n1; i1 = ni1;
        b2 = u2 ? c2v : lo; i2 = u2 ? c2i : loi;
      }
      if (l == 0) { rb1[r][w] = b1; ri1[r][w] = i1; rb2[r][w] = b2; ri2[r][w] = i2; }
    }
    __syncthreads();

    if (t < RPB) {
      float v1 = rb1[t][0], v2 = rb2[t][0]; int j1 = ri1[t][0], j2 = ri2[t][0];
      #pragma unroll
      for (int ww = 1; ww < 4; ++ww) {
        float o1 = rb1[t][ww], o2 = rb2[t][ww]; int oi1 = ri1[t][ww], oi2 = ri2[t][ww];
        bool take = (o1 < v1) || (o1 == v1 && oi1 < j1);
        float n1 = take ? o1 : v1; int ni1 = take ? oi1 : j1;
        float lo = take ? v1 : o1; int loi = take ? j1 : oi1;
        float c2v = take ? o2 : v2; int c2i = take ? oi2 : j2;
        bool u2 = (c2v < lo) || (c2v == lo && c2i < loi);
        v1 = n1; j1 = ni1; v2 = u2 ? c2v : lo; j2 = u2 ? c2i : loi;
      }
      cand[t][0] = j1; cand[t][1] = j2;
    }
    __syncthreads();

    // f64 rescore of the two candidates: wave w handles row w
    if (w < nr) {
      int c1 = cand[w][0], c2 = cand[w][1];
      float xa = xsf[l * RPB + w], xb = xsf[(l + 64) * RPB + w];
      double p1 = (double)xa * (double)embed[(size_t)c1 * DIM + l]
                + (double)xb * (double)embed[(size_t)c1 * DIM + 64 + l];
      double p2 = (double)xa * (double)embed[(size_t)c2 * DIM + l]
                + (double)xb * (double)embed[(size_t)c2 * DIM + 64 + l];
      #pragma unroll
      for (int off = 1; off < 64; off <<= 1) {
        p1 += __shfl_xor(p1, off, 64);
        p2 += __shfl_xor(p2, off, 64);
      }
      double s1 = e2d[c1] - 2.0 * p1;
      double s2 = e2d[c2] - 2.0 * p2;
      int widx = ((s2 < s1) || (s2 == s1 && c2 < c1)) ? c2 : c1;
      int row = list[base + w];
      if (l == 0) outIdx[row] = (float)widx;
      outQ[(size_t)row * DIM + l]      = embed[(size_t)widx * DIM + l];
      outQ[(size_t)row * DIM + 64 + l] = embed[(size_t)widx * DIM + 64 + l];
    }
    __syncthreads();   // xst reused next trip
  }
}

extern "C" void kernel_launch(void* const* d_in, const int* in_sizes, int n_in,
                              void* d_out, int out_size, void* d_ws, size_t ws_size,
                              hipStream_t stream) {
  const float* x     = (const float*)d_in[0];
  const float* embed = (const float*)d_in[1];
  const int N = in_sizes[0] / DIM;             // 65536 rows

  float* out    = (float*)d_out;
  float* outQ   = out;                         // [N*128] quantize
  float* outIdx = out + (size_t)N * DIM;       // [N] indices as float

  char* ws = (char*)d_ws;
  double*   e2d  = (double*)  (ws);
  float*    e2f  = (float*)   (ws + 8192);
  _Float16* eh   = (_Float16*)(ws + 12288);
  float*    eT   = (float*)   (ws + 274432);
  int*      cnt  = (int*)     (ws + 798720);
  int*      list = (int*)     (ws + 798976);

  setup_kernel  <<<NCODES / 64, 256, 0, stream>>>(embed, e2d, e2f, eh, eT, cnt);
  pass1_kernel  <<<N / TILE_M,  512, 0, stream>>>(x, embed, eh, e2f, outQ, outIdx, cnt, list);
  refine2_kernel<<<RGRID,       256, 0, stream>>>(x, embed, eT, e2d, e2f, outQ, outIdx, cnt, list);
}

// Round 7
// 140.613 us; speedup vs baseline: 1.1760x; 1.1760x over previous
//
#include <hip/hip_runtime.h>

#define DIM     128
#define NCODES  1024
#define TILE_M  64
#define BSTR    272          // LDS row stride bytes = 17 x 16 B (odd 16B-stride: conflict-free)
#define FLAGThr 0.018f       // acc-units: fp16 Hoeffding 0.010 + 2x pack err 0.008
#define RPB     4            // refine rows per block
#define RGRID   1024         // refine grid

typedef __attribute__((ext_vector_type(8))) _Float16 half8;
typedef __attribute__((ext_vector_type(4))) _Float16 half4;
typedef __attribute__((ext_vector_type(4))) float    f32x4;

// ws layout:
//      0 : e2d    (1024 double)          8 KB
//   8192 : e2f    (1024 float)           4 KB
//  12288 : eh     (1024*128 _Float16)  256 KB
// 274432 : embedT (128*1024 float)     512 KB
// 798720 : cnt    (int)
// 798976 : list   (65536 int)          256 KB

// -------- setup (fused prep+transpose): e2 f32/f64, eh fp16, embedT --------
__global__ __launch_bounds__(256) void setup_kernel(
    const float* __restrict__ embed, double* __restrict__ e2d,
    float* __restrict__ e2f, _Float16* __restrict__ eh,
    float* __restrict__ embedT, int* __restrict__ cnt)
{
  __shared__ float tile[64][132];            // 132: 16B-aligned rows, bank stride 4
  __shared__ double psum[4][64];
  if (blockIdx.x == 0 && threadIdx.x == 0) *cnt = 0;
  const int c0 = blockIdx.x * 64;            // 16 blocks x 64 codes
  const int t  = threadIdx.x;

  const f32x4* E4 = (const f32x4*)(embed + (size_t)c0 * DIM);
  #pragma unroll
  for (int i = 0; i < 8; ++i) {
    int e = t + i * 256;                     // 2048 float4s = 64x128
    int r = e >> 5, c4 = e & 31;
    f32x4 v = E4[e];
    *(f32x4*)&tile[r][c4 * 4] = v;
    half4 h;
    h[0] = (_Float16)v[0]; h[1] = (_Float16)v[1];
    h[2] = (_Float16)v[2]; h[3] = (_Float16)v[3];
    *(half4*)&eh[(size_t)(c0 + r) * DIM + c4 * 4] = h;
  }
  __syncthreads();

  // e2: 4 threads per code, 32 dims each
  {
    int r = t & 63, part = t >> 6;
    double s = 0.0;
    #pragma unroll
    for (int k = 0; k < 32; ++k) {
      float v = tile[r][part * 32 + k];
      s += (double)v * v;
    }
    psum[part][r] = s;
  }
  __syncthreads();
  if (t < 64) {
    double s = psum[0][t] + psum[1][t] + psum[2][t] + psum[3][t];
    e2d[c0 + t] = s;
    e2f[c0 + t] = (float)s;
  }

  // embedT[k][c0+c] = tile[c][k]; coalesced 256B segments per k-row
  #pragma unroll
  for (int i = 0; i < 32; ++i) {
    int idx = t + i * 256;                   // 8192 = 128k x 64c
    int k = idx >> 6, c = idx & 63;
    embedT[(size_t)k * NCODES + c0 + c] = tile[c][k];
  }
}

// -------- pass1 v6: B via LDS staging (no global latency in inner loop) ----
// acc = x.e - 0.5*e2 - 16 (init in MFMA C); argmax(acc) == argmin dist.
// Index in low 10 mantissa bits; rows with top-2 gap <= FLAGThr re-decided
// exactly by refine2. A-frags in regs (read once); B staged 256 codes at a
// time into LDS (padded 272 B rows), 1 ds_read_b128 per 4 MFMAs.
// LDS: 256*272=69632 B buffer (x-tile overlays it during prologue) + 2.3 KB
// reduction arrays -> 2 blocks/CU. launch_bounds(256,2): 256-VGPR budget.
__global__ __launch_bounds__(256, 2) void pass1_kernel(
    const float* __restrict__ x, const float* __restrict__ embed,
    const _Float16* __restrict__ eh, const float* __restrict__ e2f,
    float* __restrict__ outQ, float* __restrict__ outIdx,
    int* __restrict__ cnt, int* __restrict__ list)
{
  __shared__ __align__(16) unsigned char lds[256 * BSTR];  // x overlay, then B
  __shared__ float rb_best[4][TILE_M];
  __shared__ float rb_sec [4][TILE_M];
  __shared__ int   fidx[TILE_M];

  const int tid  = threadIdx.x;
  const int row0 = blockIdx.x * TILE_M;
  _Float16* xh = (_Float16*)lds;             // row stride 136 halves = 272 B

  // ---- prologue: stage x tile (64x128 f32 -> fp16), preload A frags ----
  {
    const f32x4* x4 = (const f32x4*)(x + (size_t)row0 * DIM);
    #pragma unroll
    for (int i = 0; i < 8; ++i) {
      int e = tid + i * 256;                 // 2048 float4s
      int r = e >> 5, c4 = e & 31;
      f32x4 v = x4[e];
      half4 h;
      h[0] = (_Float16)v[0]; h[1] = (_Float16)v[1];
      h[2] = (_Float16)v[2]; h[3] = (_Float16)v[3];
      *(half4*)&xh[r * 136 + c4 * 4] = h;
    }
  }
  __syncthreads();

  const int l  = tid & 63, w = tid >> 6;
  const int rl = l & 15,  q = l >> 4;
  const int col0 = q * 8;

  half8 afrag[4][4];
  #pragma unroll
  for (int m = 0; m < 4; ++m)
    #pragma unroll
    for (int ks = 0; ks < 4; ++ks)
      afrag[m][ks] = *(const half8*)&xh[(m * 16 + rl) * 136 + ks * 32 + col0];

  float bestp[16], secp[16];
  #pragma unroll
  for (int s = 0; s < 16; ++s) { bestp[s] = -3.0e38f; secp[s] = -3.3e38f; }

  // prefetch stage-0 B chunk (256 codes x 256 B = 64 KB) into registers
  f32x4 t0[16];
  {
    const f32x4* src = (const f32x4*)eh;
    #pragma unroll
    for (int i = 0; i < 16; ++i) t0[i] = src[tid + i * 256];
  }
  __syncthreads();                           // A-frag reads done; LDS now B buffer

  #pragma unroll
  for (int st = 0; st < 4; ++st) {
    // write staged chunk to LDS with padded rows (code = e>>4, 16B unit = e&15)
    #pragma unroll
    for (int i = 0; i < 16; ++i) {
      int e = tid + i * 256;
      *(f32x4*)&lds[(e >> 4) * BSTR + (e & 15) * 16] = t0[i];
    }
    // prefetch next stage (in flight across the barrier-adjacent window)
    f32x4 t1[16];
    if (st < 3) {
      const f32x4* src = (const f32x4*)(eh + (size_t)(st + 1) * 256 * DIM);
      #pragma unroll
      for (int i = 0; i < 16; ++i) t1[i] = src[tid + i * 256];
    }
    // e2 folded into accumulator init
    float vinit[4];
    #pragma unroll
    for (int sub = 0; sub < 4; ++sub)
      vinit[sub] = fmaf(-0.5f, e2f[st * 256 + w * 64 + sub * 16 + rl], -16.0f);

    __syncthreads();                         // B chunk visible

    #pragma unroll
    for (int sub = 0; sub < 4; ++sub) {
      const int codeL  = w * 64 + sub * 16 + rl;   // wave-private 64-code slice
      const int mycode = st * 256 + codeL;
      half8 bfrag[4];
      #pragma unroll
      for (int ks = 0; ks < 4; ++ks)
        bfrag[ks] = *(const half8*)&lds[codeL * BSTR + ks * 64 + q * 16];
      f32x4 acc[4];
      #pragma unroll
      for (int m = 0; m < 4; ++m)
        acc[m] = (f32x4){vinit[sub], vinit[sub], vinit[sub], vinit[sub]};
      #pragma unroll
      for (int ks = 0; ks < 4; ++ks)
        #pragma unroll
        for (int m = 0; m < 4; ++m)
          acc[m] = __builtin_amdgcn_mfma_f32_16x16x32_f16(afrag[m][ks], bfrag[ks], acc[m], 0, 0, 0);
      #pragma unroll
      for (int m = 0; m < 4; ++m)
        #pragma unroll
        for (int r = 0; r < 4; ++r) {
          const int s = m * 4 + r;
          float scp = __int_as_float((__float_as_int(acc[m][r]) & ~1023) | mycode);
          secp[s]  = __builtin_amdgcn_fmed3f(scp, bestp[s], secp[s]);
          bestp[s] = fmaxf(bestp[s], scp);
        }
    }
    if (st < 3) {
      __syncthreads();                       // compute done before next overwrite
      #pragma unroll
      for (int i = 0; i < 16; ++i) t0[i] = t1[i];
    }
  }

  // merge across the 16 lanes of each quarter (same rows, different codes)
  #pragma unroll
  for (int off = 1; off < 16; off <<= 1) {
    #pragma unroll
    for (int s = 0; s < 16; ++s) {
      float ob = __shfl_xor(bestp[s], off, 16);
      float os = __shfl_xor(secp[s],  off, 16);
      secp[s]  = fmaxf(__builtin_amdgcn_fmed3f(bestp[s], ob, secp[s]), os);
      bestp[s] = fmaxf(bestp[s], ob);
    }
  }
  if (rl == 0) {
    #pragma unroll
    for (int m = 0; m < 4; ++m)
      #pragma unroll
      for (int r = 0; r < 4; ++r) {
        int s = m * 4 + r;
        int row = m * 16 + q * 4 + r;
        rb_best[w][row] = bestp[s];
        rb_sec [w][row] = secp[s];
      }
  }
  __syncthreads();

  // merge the 4 waves (disjoint code sets), emit index + flag near-ties
  if (tid < TILE_M) {
    float bv = rb_best[0][tid], sv = rb_sec[0][tid];
    #pragma unroll
    for (int ww = 1; ww < 4; ++ww) {
      float ob = rb_best[ww][tid], os = rb_sec[ww][tid];
      sv = fmaxf(__builtin_amdgcn_fmed3f(bv, ob, sv), os);
      bv = fmaxf(bv, ob);
    }
    int bi = __float_as_int(bv) & 1023;
    int grow = row0 + tid;
    outIdx[grow] = (float)bi;
    fidx[tid] = bi;
    if (bv - sv <= FLAGThr) {
      int p = atomicAdd(cnt, 1);
      list[p] = grow;
    }
  }
  __syncthreads();

  // gather quantize = embed[idx] (coalesced writes, L2-hot embed reads)
  {
    const f32x4* E4   = (const f32x4*)embed;
    f32x4*       out4 = (f32x4*)(outQ + (size_t)row0 * DIM);
    #pragma unroll
    for (int i = 0; i < 8; ++i) {
      int e = tid + i * 256;
      int r = e >> 5, c4 = e & 31;
      out4[e] = E4[fidx[r] * 32 + c4];
    }
  }
}

// -------- refine v2: coalesced full f32 rescan via embedT, f64 decision -----
__global__ __launch_bounds__(256) void refine2_kernel(
    const float* __restrict__ x, const float* __restrict__ embed,
    const float* __restrict__ embedT,
    const double* __restrict__ e2d, const float* __restrict__ e2f,
    float* __restrict__ outQ, float* __restrict__ outIdx,
    const int* __restrict__ cnt, const int* __restrict__ list)
{
  __shared__ f32x4 xst[DIM];                 // xst[k][r]: k-th dim of row r
  __shared__ float rb1[RPB][4], rb2[RPB][4];
  __shared__ int   ri1[RPB][4], ri2[RPB][4];
  __shared__ int   cand[RPB][2];

  const int t = threadIdx.x;
  const int l = t & 63, w = t >> 6;
  const int n = *cnt;
  float* xsf = (float*)xst;

  for (int base = blockIdx.x * RPB; base < n; base += RGRID * RPB) {
    const int nr = min(RPB, n - base);
    // stage rows (transposed: xst[k][r])
    #pragma unroll
    for (int i = 0; i < 2; ++i) {
      int idx = t + i * 256;
      int r = idx >> 7, k = idx & 127;
      float v = 0.f;
      if (r < nr) v = x[(size_t)list[base + r] * DIM + k];
      xsf[k * RPB + r] = v;
    }
    __syncthreads();

    // thread t owns codes 4t..4t+3; fully coalesced embedT stream
    f32x4 dot[RPB];
    #pragma unroll
    for (int r = 0; r < RPB; ++r) dot[r] = (f32x4){0.f, 0.f, 0.f, 0.f};
    const f32x4* eT4 = (const f32x4*)embedT;
    #pragma unroll 4
    for (int k = 0; k < DIM; ++k) {
      f32x4 e4  = eT4[k * 256 + t];
      f32x4 xk4 = xst[k];
      #pragma unroll
      for (int r = 0; r < RPB; ++r) {
        dot[r][0] = fmaf(xk4[r], e4[0], dot[r][0]);
        dot[r][1] = fmaf(xk4[r], e4[1], dot[r][1]);
        dot[r][2] = fmaf(xk4[r], e4[2], dot[r][2]);
        dot[r][3] = fmaf(xk4[r], e4[3], dot[r][3]);
      }
    }

    // per-thread top-2 over its 4 codes, then wave + block merges
    #pragma unroll
    for (int r = 0; r < RPB; ++r) {
      float b1 = 3.4e38f, b2 = 3.4e38f; int i1 = 0, i2 = 0;
      #pragma unroll
      for (int j = 0; j < 4; ++j) {
        int c = 4 * t + j;
        float sc = fmaf(-2.0f, dot[r][j], e2f[c]);
        bool better = (sc < b1);                 // ties keep lower index
        float lv = better ? b1 : sc;  int li = better ? i1 : c;
        if (better) { b1 = sc; i1 = c; }
        bool t2 = (lv < b2) || (lv == b2 && li < i2);
        if (t2) { b2 = lv; i2 = li; }
      }
      #pragma unroll
      for (int off = 1; off < 64; off <<= 1) {
        float o1 = __shfl_xor(b1, off, 64); int oi1 = __shfl_xor(i1, off, 64);
        float o2 = __shfl_xor(b2, off, 64); int oi2 = __shfl_xor(i2, off, 64);
        bool take = (o1 < b1) || (o1 == b1 && oi1 < i1);
        float n1 = take ? o1 : b1; int ni1 = take ? oi1 : i1;
        float lo = take ? b1 : o1; int loi = take ? i1 : oi1;
        float c2v = take ? o2 : b2; int c2i = take ? oi2 : i2;
        bool u2 = (c2v < lo) || (c2v == lo && c2i < loi);
        b1 = n1; i1 = ni1;
        b2 = u2 ? c2v : lo; i2 = u2 ? c2i : loi;
      }
      if (l == 0) { rb1[r][w] = b1; ri1[r][w] = i1; rb2[r][w] = b2; ri2[r][w] = i2; }
    }
    __syncthreads();

    if (t < RPB) {
      float v1 = rb1[t][0], v2 = rb2[t][0]; int j1 = ri1[t][0], j2 = ri2[t][0];
      #pragma unroll
      for (int ww = 1; ww < 4; ++ww) {
        float o1 = rb1[t][ww], o2 = rb2[t][ww]; int oi1 = ri1[t][ww], oi2 = ri2[t][ww];
        bool take = (o1 < v1) || (o1 == v1 && oi1 < j1);
        float n1 = take ? o1 : v1; int ni1 = take ? oi1 : j1;
        float lo = take ? v1 : o1; int loi = take ? j1 : oi1;
        float c2v = take ? o2 : v2; int c2i = take ? oi2 : j2;
        bool u2 = (c2v < lo) || (c2v == lo && c2i < loi);
        v1 = n1; j1 = ni1; v2 = u2 ? c2v : lo; j2 = u2 ? c2i : loi;
      }
      cand[t][0] = j1; cand[t][1] = j2;
    }
    __syncthreads();

    // f64 rescore of the two candidates: wave w handles row w
    if (w < nr) {
      int c1 = cand[w][0], c2 = cand[w][1];
      float xa = xsf[l * RPB + w], xb = xsf[(l + 64) * RPB + w];
      double p1 = (double)xa * (double)embed[(size_t)c1 * DIM + l]
                + (double)xb * (double)embed[(size_t)c1 * DIM + 64 + l];
      double p2 = (double)xa * (double)embed[(size_t)c2 * DIM + l]
                + (double)xb * (double)embed[(size_t)c2 * DIM + 64 + l];
      #pragma unroll
      for (int off = 1; off < 64; off <<= 1) {
        p1 += __shfl_xor(p1, off, 64);
        p2 += __shfl_xor(p2, off, 64);
      }
      double s1 = e2d[c1] - 2.0 * p1;
      double s2 = e2d[c2] - 2.0 * p2;
      int widx = ((s2 < s1) || (s2 == s1 && c2 < c1)) ? c2 : c1;
      int row = list[base + w];
      if (l == 0) outIdx[row] = (float)widx;
      outQ[(size_t)row * DIM + l]      = embed[(size_t)widx * DIM + l];
      outQ[(size_t)row * DIM + 64 + l] = embed[(size_t)widx * DIM + 64 + l];
    }
    __syncthreads();   // xst reused next trip
  }
}

extern "C" void kernel_launch(void* const* d_in, const int* in_sizes, int n_in,
                              void* d_out, int out_size, void* d_ws, size_t ws_size,
                              hipStream_t stream) {
  const float* x     = (const float*)d_in[0];
  const float* embed = (const float*)d_in[1];
  const int N = in_sizes[0] / DIM;             // 65536 rows

  float* out    = (float*)d_out;
  float* outQ   = out;                         // [N*128] quantize
  float* outIdx = out + (size_t)N * DIM;       // [N] indices as float

  char* ws = (char*)d_ws;
  double*   e2d  = (double*)  (ws);
  float*    e2f  = (float*)   (ws + 8192);
  _Float16* eh   = (_Float16*)(ws + 12288);
  float*    eT   = (float*)   (ws + 274432);
  int*      cnt  = (int*)     (ws + 798720);
  int*      list = (int*)     (ws + 798976);

  setup_kernel  <<<NCODES / 64, 256, 0, stream>>>(embed, e2d, e2f, eh, eT, cnt);
  pass1_kernel  <<<N / TILE_M,  256, 0, stream>>>(x, embed, eh, e2f, outQ, outIdx, cnt, list);
  refine2_kernel<<<RGRID,       256, 0, stream>>>(x, embed, eT, e2d, e2f, outQ, outIdx, cnt, list);
}